// Round 9
// baseline (380.979 us; speedup 1.0000x reference)
//
#include <hip/hip_runtime.h>
#include <hip/hip_cooperative_groups.h>
#include <hip/hip_bf16.h>
#include <math.h>

namespace cg = cooperative_groups;

// Problem constants
constexpr int B    = 4;
constexpr int D    = 768;
constexpr int HW   = 1024;
constexpr int M    = B * HW;        // 4096 queries
constexpr int NDB  = 20000;
constexpr int LT   = 158;           // 128-row layout tiles (20224 rows padded)
constexpr int OUTH = 512;
constexpr int OUTW = 512;

constexpr int BM     = 256;         // db rows per gemm tile (2 layout tiles)
constexpr int BN     = 128;         // queries per tile
constexpr int KSTEPS = D / 64;      // 12 64-K steps
constexpr int NSPLIT = 8;
constexpr int NT2    = 79;          // 256-row gemm tiles
constexpr int STEPB  = 128 * 64;    // 8192 B per 64-K step-block (one layout tile)
constexpr int NBLK   = 256;         // cooperative grid: 1 block/CU guaranteed
constexpr int NUNITS = LT * KSTEPS + 32 * KSTEPS;  // 1896 + 384 = 2280

typedef int   i32x8  __attribute__((ext_vector_type(8)));
typedef float f32x16 __attribute__((ext_vector_type(16)));

__device__ __forceinline__ void insert3(float& t0, float& t1, float& t2, float d) {
    float a0 = fminf(d, t0);
    float b0 = fmaxf(d, t0);
    float a1 = fminf(b0, t1);
    float b1 = fmaxf(b0, t1);
    t0 = a0; t1 = a1;
    t2 = fminf(b1, t2);
}

__device__ __forceinline__ unsigned int pack4_fp8(float a, float b, float c, float d) {
    int v = __builtin_amdgcn_cvt_pk_fp8_f32(a, b, 0, false);
    v = __builtin_amdgcn_cvt_pk_fp8_f32(c, d, v, true);
    return (unsigned int)v;
}

__device__ __forceinline__ void gl_lds16(const unsigned char* g, unsigned char* l) {
    __builtin_amdgcn_global_load_lds(
        (const __attribute__((address_space(1))) void*)g,
        (__attribute__((address_space(3))) void*)l, 16, 0, 0);
}

// ===========================================================================
// PHASE 1: fp32 -> fp8 tiled conversion of db and q, + x2/q2 partials
__device__ void phase1_convert(int bid, int t, unsigned char* smem,
                               const float* __restrict__ emb,
                               const float* __restrict__ db,
                               unsigned char* __restrict__ dbt8,
                               unsigned char* __restrict__ qbt8,
                               float* __restrict__ x2p,
                               float* __restrict__ q2p) {
    float (*panel)[68] = (float(*)[68])smem;           // 34816 B
    float* part        = (float*)(smem + 34816);       // 2048 B

    for (int u = bid; u < NUNITS; u += NBLK) {
        if (u < LT * KSTEPS) {
            // ---- db unit: layout tile lt, k-step g ----
            const int lt = u / KSTEPS;
            const int g  = u - lt * KSTEPS;
            const int n0 = lt * 128;
            #pragma unroll
            for (int pass = 0; pass < 8; ++pass) {
                int idx = pass * 256 + t;            // 0..2047
                int row = idx >> 4, c4 = idx & 15;
                int n = n0 + row;
                float4 v = make_float4(0.f, 0.f, 0.f, 0.f);
                if (n < NDB) v = *(const float4*)(db + (size_t)n * D + g * 64 + c4 * 4);
                *(float4*)&panel[row][c4 * 4] = v;
            }
            __syncthreads();
            #pragma unroll
            for (int pass = 0; pass < 2; ++pass) {
                int idx = pass * 256 + t;            // bits [rg:2][h2:1][kc:1][r:5]
                int r  = idx & 31;
                int kc = (idx >> 5) & 1;
                int h2 = (idx >> 6) & 1;
                int rg = idx >> 7;
                int row  = rg * 32 + r;
                int kloc = kc * 32 + h2 * 16;
                float4 va = *(const float4*)&panel[row][kloc + 0];
                float4 vb = *(const float4*)&panel[row][kloc + 4];
                float4 vc = *(const float4*)&panel[row][kloc + 8];
                float4 vd = *(const float4*)&panel[row][kloc + 12];
                float ss = va.x*va.x + va.y*va.y + va.z*va.z + va.w*va.w
                         + vb.x*vb.x + vb.y*vb.y + vb.z*vb.z + vb.w*vb.w
                         + vc.x*vc.x + vc.y*vc.y + vc.z*vc.z + vc.w*vc.w
                         + vd.x*vd.x + vd.y*vd.y + vd.z*vd.z + vd.w*vd.w;
                uint4 o;
                o.x = pack4_fp8(va.x, va.y, va.z, va.w);
                o.y = pack4_fp8(vb.x, vb.y, vb.z, vb.w);
                o.z = pack4_fp8(vc.x, vc.y, vc.z, vc.w);
                o.w = pack4_fp8(vd.x, vd.y, vd.z, vd.w);
                ((uint4*)dbt8)[((size_t)lt * KSTEPS + g) * 512 + idx] = o;
                part[idx] = ss;
            }
            __syncthreads();
            if (t < 128) {
                int base = (t >> 5) * 128 + (t & 31);
                float s = part[base] + part[base + 32] + part[base + 64] + part[base + 96];
                x2p[((size_t)lt * KSTEPS + g) * 128 + t] = s;
            }
            __syncthreads();
        } else {
            // ---- q unit: qtile qt, k-step g ----
            const int v2 = u - LT * KSTEPS;
            const int qt = v2 / KSTEPS;
            const int g  = v2 - qt * KSTEPS;
            const int b  = qt >> 3;
            const int p0 = (qt & 7) * 128;
            #pragma unroll
            for (int pass = 0; pass < 2; ++pass) {
                int idx = pass * 256 + t;
                int r  = idx & 31;
                int kc = (idx >> 5) & 1;
                int h2 = (idx >> 6) & 1;
                int rg = idx >> 7;
                int prow = rg * 32 + r;
                int kb = g * 64 + kc * 32 + h2 * 16;
                const float* src = emb + ((size_t)b * D + kb) * HW + p0 + prow;
                float v[16];
                float ss = 0.f;
                #pragma unroll
                for (int j = 0; j < 16; ++j) {
                    v[j] = src[(size_t)j * HW];
                    ss = fmaf(v[j], v[j], ss);
                }
                uint4 o;
                o.x = pack4_fp8(-2.f*v[0],  -2.f*v[1],  -2.f*v[2],  -2.f*v[3]);
                o.y = pack4_fp8(-2.f*v[4],  -2.f*v[5],  -2.f*v[6],  -2.f*v[7]);
                o.z = pack4_fp8(-2.f*v[8],  -2.f*v[9],  -2.f*v[10], -2.f*v[11]);
                o.w = pack4_fp8(-2.f*v[12], -2.f*v[13], -2.f*v[14], -2.f*v[15]);
                ((uint4*)qbt8)[((size_t)qt * KSTEPS + g) * 512 + idx] = o;
                part[idx] = ss;
            }
            __syncthreads();
            if (t < 128) {
                int base = (t >> 5) * 128 + (t & 31);
                float s = part[base] + part[base + 32] + part[base + 64] + part[base + 96];
                q2p[((size_t)qt * KSTEPS + g) * 128 + t] = s;
            }
            __syncthreads();
        }
    }
}

// ===========================================================================
// PHASE 2: MX-fp8 MFMA GEMM (256x128 tiles), pipelined LDS dbuf, fused top-3
__device__ void phase2_gemm(int bid, int tid, unsigned char* smem,
                            const unsigned char* __restrict__ dbt8,
                            const unsigned char* __restrict__ qbt8,
                            const float* __restrict__ x2p,
                            float* __restrict__ partials) {
    unsigned char* Asm = smem;                         // 2*16384
    unsigned char* Bsm = smem + 32768;                 // 2*8192
    float* X2s  = (float*)(smem + 49152);              // 256 floats
    float* redp = (float*)(smem + 50176);              // 4*128*3 floats

    const int lane = tid & 63;
    const int w    = tid >> 6;           // 0..3
    const int lts  = w >> 1;             // 128-row layout half
    const int wr   = w & 1;
    const int h    = lane >> 5;
    const int l31  = lane & 31;

    const int sp    = bid & 7;           // split 0..7 (== XCD slot)
    const int qtile = bid >> 3;          // 0..31
    const int m0    = qtile * BN;

    int a_off[2], b_off[4];
    #pragma unroll
    for (int i = 0; i < 2; ++i) a_off[i] = lts * 8192 + (wr * 2 + i) * 2048 + h * 512 + l31 * 16;
    #pragma unroll
    for (int j4 = 0; j4 < 4; ++j4) b_off[j4] = j4 * 2048 + h * 512 + l31 * 16;

    const unsigned char* aNext = dbt8 + (size_t)(2 * sp + lts) * KSTEPS * STEPB + wr * 4096 + lane * 16;
    const unsigned char* bNext = qbt8 + (size_t)qtile * KSTEPS * STEPB + w * 2048 + lane * 16;
    unsigned char* aDst = Asm + w * 4096;   // +buf*16384
    unsigned char* bDst = Bsm + w * 2048;   // +buf*8192

    // prologue: stage (sp, 0) into buf 0
    #pragma unroll
    for (int l = 0; l < 4; ++l) gl_lds16(aNext + l * 1024, aDst + l * 1024);
    #pragma unroll
    for (int l = 0; l < 2; ++l) gl_lds16(bNext + l * 1024, bDst + l * 1024);

    float t0[4], t1[4], t2[4];
    #pragma unroll
    for (int j4 = 0; j4 < 4; ++j4) { t0[j4] = INFINITY; t1[j4] = INFINITY; t2[j4] = INFINITY; }

    for (int tile = sp; tile < NT2; tile += NSPLIT) {
        __syncthreads();   // previous tile's epilogue done reading X2s
        {   // fused x2 reduction: X2s[row] = sum of 12 partials (pad -> 1e30)
            int n = tile * BM + tid;
            float s = 1e30f;
            if (n < NDB) {
                const float* p = x2p + (size_t)(n >> 7) * (KSTEPS * 128) + (n & 127);
                s = 0.f;
                #pragma unroll
                for (int g = 0; g < KSTEPS; ++g) s += p[g * 128];
            }
            X2s[tid] = s;
        }

        f32x16 acc[2][4];
        #pragma unroll
        for (int i = 0; i < 2; ++i)
            #pragma unroll
            for (int j4 = 0; j4 < 4; ++j4)
                #pragma unroll
                for (int r = 0; r < 16; ++r) acc[i][j4][r] = 0.f;

        const bool lastTile = (tile + NSPLIT >= NT2);

        #pragma unroll 2
        for (int g = 0; g < KSTEPS; ++g) {
            const int cur = g & 1;
            __syncthreads();   // stage(g) landed; buf[cur^1] readers done
            if (g < KSTEPS - 1) {
                aNext += STEPB;
                bNext += STEPB;
                unsigned char* ad = aDst + (cur ^ 1) * 16384;
                unsigned char* bd = bDst + (cur ^ 1) * 8192;
                #pragma unroll
                for (int l = 0; l < 4; ++l) gl_lds16(aNext + l * 1024, ad + l * 1024);
                #pragma unroll
                for (int l = 0; l < 2; ++l) gl_lds16(bNext + l * 1024, bd + l * 1024);
            } else if (!lastTile) {
                aNext += (size_t)(2 * NSPLIT) * KSTEPS * STEPB - (size_t)(KSTEPS - 1) * STEPB;
                bNext -= (size_t)(KSTEPS - 1) * STEPB;
                unsigned char* ad = aDst + (cur ^ 1) * 16384;
                unsigned char* bd = bDst + (cur ^ 1) * 8192;
                #pragma unroll
                for (int l = 0; l < 4; ++l) gl_lds16(aNext + l * 1024, ad + l * 1024);
                #pragma unroll
                for (int l = 0; l < 2; ++l) gl_lds16(bNext + l * 1024, bd + l * 1024);
            }
            const unsigned char* Ab = Asm + cur * 16384;
            const unsigned char* Bb = Bsm + cur * 8192;
            i32x8 af[2], bf[4];
            #pragma unroll
            for (int i = 0; i < 2; ++i) {
                int4 lo = *(const int4*)(Ab + a_off[i]);
                int4 hi = *(const int4*)(Ab + a_off[i] + 1024);
                af[i] = (i32x8){lo.x, lo.y, lo.z, lo.w, hi.x, hi.y, hi.z, hi.w};
            }
            #pragma unroll
            for (int j4 = 0; j4 < 4; ++j4) {
                int4 lo = *(const int4*)(Bb + b_off[j4]);
                int4 hi = *(const int4*)(Bb + b_off[j4] + 1024);
                bf[j4] = (i32x8){lo.x, lo.y, lo.z, lo.w, hi.x, hi.y, hi.z, hi.w};
            }
            #pragma unroll
            for (int i = 0; i < 2; ++i)
                #pragma unroll
                for (int j4 = 0; j4 < 4; ++j4)
                    acc[i][j4] = __builtin_amdgcn_mfma_scale_f32_32x32x64_f8f6f4(
                        af[i], bf[j4], acc[i][j4], 0, 0,
                        0, 0x7f7f7f7f, 0, 0x7f7f7f7f);
        }

        // epilogue: rows = w*64 + i*32 + rg2*8 + 4h + rr
        #pragma unroll
        for (int i = 0; i < 2; ++i) {
            #pragma unroll
            for (int rg2 = 0; rg2 < 4; ++rg2) {
                float4 xv = *(const float4*)&X2s[w * 64 + i * 32 + rg2 * 8 + 4 * h];
                #pragma unroll
                for (int j4 = 0; j4 < 4; ++j4) {
                    #pragma unroll
                    for (int rr = 0; rr < 4; ++rr) {
                        float s = acc[i][j4][rg2 * 4 + rr] + ((const float*)&xv)[rr];
                        insert3(t0[j4], t1[j4], t2[j4], s);
                    }
                }
            }
        }
    }

    // merge across row-halves (lane^32; col = l31 preserved)
    #pragma unroll
    for (int j4 = 0; j4 < 4; ++j4) {
        float o0 = __shfl_xor(t0[j4], 32);
        float o1 = __shfl_xor(t1[j4], 32);
        float o2 = __shfl_xor(t2[j4], 32);
        insert3(t0[j4], t1[j4], t2[j4], o0);
        insert3(t0[j4], t1[j4], t2[j4], o1);
        insert3(t0[j4], t1[j4], t2[j4], o2);
    }
    if (h == 0) {
        #pragma unroll
        for (int j4 = 0; j4 < 4; ++j4) {
            int col = j4 * 32 + l31;
            redp[(w * BN + col) * 3 + 0] = t0[j4];
            redp[(w * BN + col) * 3 + 1] = t1[j4];
            redp[(w * BN + col) * 3 + 2] = t2[j4];
        }
    }
    __syncthreads();
    if (tid < BN) {
        float a0 = redp[tid * 3 + 0], a1 = redp[tid * 3 + 1], a2 = redp[tid * 3 + 2];
        #pragma unroll
        for (int ww = 1; ww < 4; ++ww) {
            insert3(a0, a1, a2, redp[(ww * BN + tid) * 3 + 0]);
            insert3(a0, a1, a2, redp[(ww * BN + tid) * 3 + 1]);
            insert3(a0, a1, a2, redp[(ww * BN + tid) * 3 + 2]);
        }
        float* dst = partials + ((size_t)(m0 + tid) * NSPLIT + sp) * 3;
        dst[0] = a0; dst[1] = a1; dst[2] = a2;
    }
}

// ===========================================================================
// PHASE 3: merge partials + q2 -> ood (replicated per block) + bilinear x16
__device__ void phase3_out(int bid, int t, unsigned char* smem,
                           const float* __restrict__ partials,
                           const float* __restrict__ q2p,
                           float* __restrict__ out) {
    float* oodc = (float*)smem;          // 3 rows x 32 cols
    const int bb  = bid >> 6;            // batch 0..3
    const int blk = bid & 63;            // 0..63
    const int oy0 = blk * 8;             // 8 output rows per block
    const float syb = (oy0 + 0.5f) * (1.f / 16.f) - 0.5f;
    const int f = (int)floorf(syb);      // all 8 rows use source rows f, f+1

    if (t < 96) {
        int ci = t >> 5, x = t & 31;
        int y = min(max(f + ci, 0), 31);
        int m = bb * 1024 + y * 32 + x;
        const float* pp = partials + (size_t)m * NSPLIT * 3;
        float a0 = INFINITY, a1 = INFINITY, a2 = INFINITY;
        #pragma unroll
        for (int j = 0; j < NSPLIT * 3; ++j) insert3(a0, a1, a2, pp[j]);
        const float* qp = q2p + (size_t)(m >> 7) * (KSTEPS * 128) + (m & 127);
        float q = 0.f;
        #pragma unroll
        for (int g = 0; g < KSTEPS; ++g) q += qp[g * 128];
        float d0 = sqrtf(fmaxf(q + a0, 1e-12f));
        float d1 = sqrtf(fmaxf(q + a1, 1e-12f));
        float d2 = sqrtf(fmaxf(q + a2, 1e-12f));
        oodc[ci * 32 + x] = (d0 + d1 + d2) * (1.f / 3.f);
    }
    __syncthreads();

    // each thread: 16 consecutive pixels in one output row
    const int p0  = t * 16;
    const int oy  = oy0 + (p0 >> 9);
    const int ox0 = p0 & 511;
    float sy = (oy + 0.5f) * (1.f / 16.f) - 0.5f;
    int g0 = (int)floorf(sy);
    float wy = sy - (float)g0;
    const float* rowA = oodc + (g0 - f) * 32;
    const float* rowB = rowA + 32;
    float vout[16];
    #pragma unroll
    for (int k = 0; k < 16; ++k) {
        int ox = ox0 + k;
        float sx = (ox + 0.5f) * (1.f / 16.f) - 0.5f;
        float fx = floorf(sx);
        float wx = sx - fx;
        int x0 = max(0, min(31, (int)fx));
        int x1 = max(0, min(31, (int)fx + 1));
        float top = rowA[x0] + wx * (rowA[x1] - rowA[x0]);
        float bot = rowB[x0] + wx * (rowB[x1] - rowB[x0]);
        vout[k] = top + wy * (bot - top);
    }
    float* dst = out + (size_t)bid * 4096 + p0;
    #pragma unroll
    for (int k = 0; k < 4; ++k)
        *(float4*)(dst + k * 4) = *(float4*)&vout[k * 4];
}

// ===========================================================================
// Fused cooperative kernel (256 blocks = 1/CU, always launchable)
__global__ __launch_bounds__(256) void fused_knn(const float* __restrict__ emb,
                                                 const float* __restrict__ db,
                                                 unsigned char* __restrict__ dbt8,
                                                 unsigned char* __restrict__ qbt8,
                                                 float* __restrict__ x2p,
                                                 float* __restrict__ q2p,
                                                 float* __restrict__ partials,
                                                 float* __restrict__ out) {
    __shared__ __align__(16) unsigned char smem[56320];
    const int t   = threadIdx.x;
    const int bid = blockIdx.x;
    cg::grid_group grid = cg::this_grid();

    phase1_convert(bid, t, smem, emb, db, dbt8, qbt8, x2p, q2p);
    __threadfence();
    grid.sync();
    phase2_gemm(bid, t, smem, dbt8, qbt8, x2p, partials);
    __threadfence();
    grid.sync();
    phase3_out(bid, t, smem, partials, q2p, out);
}

// Fallback: same phases as ordinary kernels (if cooperative launch fails)
__global__ __launch_bounds__(256) void k_phase1(const float* __restrict__ emb,
                                                const float* __restrict__ db,
                                                unsigned char* __restrict__ dbt8,
                                                unsigned char* __restrict__ qbt8,
                                                float* __restrict__ x2p,
                                                float* __restrict__ q2p) {
    __shared__ __align__(16) unsigned char smem[36864];
    phase1_convert(blockIdx.x, threadIdx.x, smem, emb, db, dbt8, qbt8, x2p, q2p);
}
__global__ __launch_bounds__(256) void k_phase2(const unsigned char* __restrict__ dbt8,
                                                const unsigned char* __restrict__ qbt8,
                                                const float* __restrict__ x2p,
                                                float* __restrict__ partials) {
    __shared__ __align__(16) unsigned char smem[56320];
    phase2_gemm(blockIdx.x, threadIdx.x, smem, dbt8, qbt8, x2p, partials);
}
__global__ __launch_bounds__(256) void k_phase3(const float* __restrict__ partials,
                                                const float* __restrict__ q2p,
                                                float* __restrict__ out) {
    __shared__ __align__(16) unsigned char smem[512];
    phase3_out(blockIdx.x, threadIdx.x, smem, partials, q2p, out);
}

// ---------------------------------------------------------------------------
extern "C" void kernel_launch(void* const* d_in, const int* in_sizes, int n_in,
                              void* d_out, int out_size, void* d_ws, size_t ws_size,
                              hipStream_t stream) {
    const float* emb = (const float*)d_in[0];
    const float* db  = (const float*)d_in[1];
    float* out = (float*)d_out;

    // workspace layout (bytes), total ~20.2 MB
    char* ws = (char*)d_ws;
    unsigned char* dbt8 = (unsigned char*)ws;                    // 158*12*8192 = 15,532,032
    unsigned char* qbt8 = (unsigned char*)(ws + 15532032);       // 32*12*8192  =  3,145,728
    float* x2p      = (float*)(ws + 18677760);                   // 158*12*128*4 = 970,752
    float* q2p      = (float*)(ws + 19648512);                   // 32*12*128*4 = 196,608
    float* partials = (float*)(ws + 19845120);                   // 4096*8*3*4 = 393,216

    void* args[] = { (void*)&emb, (void*)&db, (void*)&dbt8, (void*)&qbt8,
                     (void*)&x2p, (void*)&q2p, (void*)&partials, (void*)&out };
    hipError_t err = hipLaunchCooperativeKernel((void*)fused_knn, dim3(NBLK), dim3(256),
                                                args, 0, stream);
    if (err != hipSuccess) {
        (void)hipGetLastError();   // clear sticky error, run split fallback
        k_phase1<<<NBLK, 256, 0, stream>>>(emb, db, dbt8, qbt8, x2p, q2p);
        k_phase2<<<NBLK, 256, 0, stream>>>(dbt8, qbt8, x2p, partials);
        k_phase3<<<NBLK, 256, 0, stream>>>(partials, q2p, out);
    }
}